// Round 6
// baseline (1546.245 us; speedup 1.0000x reference)
//
#include <hip/hip_runtime.h>
#include <hip/hip_bf16.h>
#include <stdint.h>

// Problem dims
#define Bg 256
#define Tg 64
#define Pg 10
#define NG 8   // graphs per sgcn block

__device__ __forceinline__ uint16_t f2bf(float f) {
    union { float f; uint32_t i; } v; v.f = f;
    uint32_t lsb = (v.i >> 16) & 1u;
    return (uint16_t)((v.i + 0x7FFFu + lsb) >> 16);
}
__device__ __forceinline__ float bf2f(uint16_t u) {
    union { uint32_t i; float f; } v; v.i = ((uint32_t)u) << 16; return v.f;
}
__device__ __forceinline__ float sigmoidf_(float x) {
    return 1.0f / (1.0f + __expf(-x));
}
__device__ __forceinline__ float fast_tanh(float x) {
    // |pre-activation| is bounded (~10) here; no overflow risk at e^{2x}
    float e = __expf(2.0f * x);
    return (e - 1.0f) / (e + 1.0f);
}

// ---------------------------------------------------------------------------
// SGCN v3: 8 graphs/block, 512 threads (8 waves/CU). Thread = (g, s, k).
// Linearity used in BOTH base and deep layers: (An@H)@Wblk == An@(H@Wblk),
// so no aggregate arrays are materialized; per-thread U/D accumulators in
// registers; H ping-pong buffers (no copy pass). Weights fp32 in LDS.
// LDS total ~151 KB -> 1 block/CU but 2 waves/SIMD.
// ---------------------------------------------------------------------------
__global__ __launch_bounds__(512) void sgcn_kernel(
    const float* __restrict__ x,
    const float* __restrict__ A_pos,
    const float* __restrict__ A_neg,
    const float* __restrict__ Wpb,
    const float* __restrict__ bpb,
    const float* __restrict__ Wnb,
    const float* __restrict__ bnb,
    const float* __restrict__ Wpd,
    const float* __restrict__ bpd,
    const float* __restrict__ Wnd,
    const float* __restrict__ bnd,
    uint16_t* __restrict__ z)
{
    __shared__ __align__(16) float WL[16384];            // 64 KB weight stage
    __shared__ float As[NG][2][10][10];                  // 6.4 KB norm. adj
    __shared__ float rsv[NG][2][10];
    __shared__ __align__(16) float Xs[NG][10][128];      // 40 KB
    __shared__ __align__(16) float Ha[NG][2][10][32];    // 20 KB (ping)
    __shared__ __align__(16) float Hb[NG][2][10][32];    // 20 KB (pong)

    const int tid = threadIdx.x;
    const int bt0 = blockIdx.x * NG;
    const int g = tid >> 6;          // wave-uniform graph
    const int s = (tid >> 5) & 1;    // sign
    const int k = tid & 31;          // output column

    // ---- stage base weights [s][d(0..255)][k], coalesced float4 ----
    {
        const float4* wp = reinterpret_cast<const float4*>(Wpb);
        const float4* wn = reinterpret_cast<const float4*>(Wnb);
        float4* wl = reinterpret_cast<float4*>(WL);
        for (int e = tid; e < 4096; e += 512)
            wl[e] = (e < 2048) ? wp[e] : wn[e - 2048];
    }
    // ---- load X ----
    {
        float4* xs = reinterpret_cast<float4*>(&Xs[0][0][0]);
        for (int e = tid; e < NG * 320; e += 512) {
            int gg = e / 320, r = e - gg * 320;
            xs[e] = reinterpret_cast<const float4*>(
                x + (size_t)(bt0 + gg) * 1280)[r];
        }
    }
    // ---- load raw adjacencies ----
    for (int e = tid; e < NG * 200; e += 512) {
        int gg = e / 200, r = e - gg * 200;
        int sg = r / 100, rr = r - sg * 100;
        (&As[gg][sg][0][0])[rr] =
            (sg ? A_neg : A_pos)[(size_t)(bt0 + gg) * 100 + rr];
    }
    __syncthreads();
    if (tid < NG * 20) {
        int gg = tid / 20, r = tid % 20, sg = r / 10, i = r % 10;
        float sum = 0.f;
        #pragma unroll
        for (int j = 0; j < 10; ++j) sum += As[gg][sg][i][j];
        rsv[gg][sg][i] = 1.0f / (sum + 1e-8f);
    }
    __syncthreads();
    for (int e = tid; e < NG * 200; e += 512) {
        int gg = e / 200, r = e - gg * 200;
        int sg = r / 100, rr = r - sg * 100;
        As[gg][sg][rr / 10][rr % 10] *= rsv[gg][sg][rr / 10];
    }
    __syncthreads();

    // ---- base layer: Y=X@Wtop, Z=X@Wbot (regs); H=tanh(An@Y + Z + b) ----
    {
        float accY[10], accZ[10];
        #pragma unroll
        for (int i = 0; i < 10; ++i) { accY[i] = 0.f; accZ[i] = 0.f; }
        const float* Wt = &WL[s * 8192 + k];
        for (int d = 0; d < 128; d += 4) {
            float wt0 = Wt[(d + 0) * 32], wt1 = Wt[(d + 1) * 32];
            float wt2 = Wt[(d + 2) * 32], wt3 = Wt[(d + 3) * 32];
            float wb0 = Wt[(d + 128) * 32], wb1 = Wt[(d + 129) * 32];
            float wb2 = Wt[(d + 130) * 32], wb3 = Wt[(d + 131) * 32];
            #pragma unroll
            for (int i = 0; i < 10; ++i) {
                float4 xv = *reinterpret_cast<const float4*>(&Xs[g][i][d]);
                accY[i] += xv.x * wt0 + xv.y * wt1 + xv.z * wt2 + xv.w * wt3;
                accZ[i] += xv.x * wb0 + xv.y * wb1 + xv.z * wb2 + xv.w * wb3;
            }
        }
        float bb = (s ? bnb : bpb)[k];
        #pragma unroll
        for (int i = 0; i < 10; ++i) {
            float acc = accZ[i] + bb;
            #pragma unroll
            for (int j = 0; j < 10; ++j)
                acc += As[g][s][i][j] * accY[j];
            Ha[g][s][i][k] = fast_tanh(acc);
        }
    }
    __syncthreads();

    // ---- two deep layers (ping-pong Ha/Hb, no copy) ----
    for (int l = 0; l < 2; ++l) {
        // restage deep weights [s][rk(0..223)][k]
        {
            const float4* wp = reinterpret_cast<const float4*>(Wpd + l * 7168);
            const float4* wn = reinterpret_cast<const float4*>(Wnd + l * 7168);
            float4* wl = reinterpret_cast<float4*>(WL);
            for (int e = tid; e < 3584; e += 512)
                wl[e] = (e < 1792) ? wp[e] : wn[e - 1792];
        }
        __syncthreads();

        const float* Hin = l ? &Hb[0][0][0][0] : &Ha[0][0][0][0];
        float*      Hout = l ? &Ha[0][0][0][0] : &Hb[0][0][0][0];

        // U12[j] = (Hp@W0 + Hn@W1)[j][k]   (aggregated later with An_p)
        // U34[j] = (Hp@W2 + Hn@W3)[j][k]   (aggregated later with An_n)
        // D[j]   = (Hp@W4 + Hn@W5 + Hsel@W6)[j][k]  (direct terms)
        float U12[10], U34[10], D[10];
        #pragma unroll
        for (int i = 0; i < 10; ++i) { U12[i] = 0.f; U34[i] = 0.f; D[i] = 0.f; }
        const float* Wd = &WL[s * 7168 + k];
        const float* hpb = Hin + g * 640;        // [g][0][j][c]
        const float* hnb = Hin + g * 640 + 320;  // [g][1][j][c]
        for (int c = 0; c < 32; c += 2) {
            float w10 = Wd[(0 * 32 + c) * 32], w11 = Wd[(0 * 32 + c + 1) * 32];
            float w20 = Wd[(1 * 32 + c) * 32], w21 = Wd[(1 * 32 + c + 1) * 32];
            float w30 = Wd[(2 * 32 + c) * 32], w31 = Wd[(2 * 32 + c + 1) * 32];
            float w40 = Wd[(3 * 32 + c) * 32], w41 = Wd[(3 * 32 + c + 1) * 32];
            float w50 = Wd[(4 * 32 + c) * 32], w51 = Wd[(4 * 32 + c + 1) * 32];
            float w60 = Wd[(5 * 32 + c) * 32], w61 = Wd[(5 * 32 + c + 1) * 32];
            float w70 = Wd[(6 * 32 + c) * 32], w71 = Wd[(6 * 32 + c + 1) * 32];
            #pragma unroll
            for (int j = 0; j < 10; ++j) {
                float2 hp = *reinterpret_cast<const float2*>(hpb + j * 32 + c);
                float2 hn = *reinterpret_cast<const float2*>(hnb + j * 32 + c);
                float2 hs = s ? hn : hp;
                U12[j] += hp.x * w10 + hp.y * w11 + hn.x * w20 + hn.y * w21;
                U34[j] += hp.x * w30 + hp.y * w31 + hn.x * w40 + hn.y * w41;
                D[j]   += hp.x * w50 + hp.y * w51 + hn.x * w60 + hn.y * w61
                        + hs.x * w70 + hs.y * w71;
            }
        }
        float bb = (s ? bnd : bpd)[l * 32 + k];
        #pragma unroll
        for (int i = 0; i < 10; ++i) {
            float acc = D[i] + bb;
            #pragma unroll
            for (int j = 0; j < 10; ++j)
                acc += As[g][0][i][j] * U12[j] + As[g][1][i][j] * U34[j];
            Hout[g * 640 + s * 320 + i * 32 + k] = fast_tanh(acc);
        }
        __syncthreads();
    }

    // ---- z = cat([h_pos, h_neg], -1) as bf16 (final H is in Ha) ----
    {
        uint16_t* zb = z + (size_t)bt0 * 640;
        for (int e = tid; e < NG * 640; e += 512) {
            int gg = e / 640, r = e - gg * 640;
            int i = r >> 6, cc = r & 63, ss = cc >> 5, kk2 = cc & 31;
            zb[e] = f2bf(Ha[gg][ss][i][kk2]);
        }
    }
}

// ---------------------------------------------------------------------------
// LSTM v2: 2 games/block -> 1280 blocks (~4 co-resident/CU) for barrier
// overlap. Thread g owns gate row g, weights bf16-packed in 64 VGPRs.
// __launch_bounds__(256,4) caps VGPRs at 128 for 16 waves/CU.
// ---------------------------------------------------------------------------
__global__ __launch_bounds__(256, 4) void lstm_kernel(
    const uint16_t* __restrict__ zin,
    const float* __restrict__ W_ih,
    const float* __restrict__ W_hh,
    const float* __restrict__ b_ih,
    const float* __restrict__ b_hh,
    float* __restrict__ out)
{
    __shared__ __align__(16) float zh[2][128];   // per game: [z(64) | h(64)]
    __shared__ float gbuf[2][256];               // gate pre-activations

    const int tid = threadIdx.x;
    const int p   = blockIdx.x % 10;
    const int b0  = (blockIdx.x / 10) * 2;

    uint32_t wreg[64];
    {
        const float4* wi4 = reinterpret_cast<const float4*>(
            W_ih + ((size_t)p * 256 + tid) * 64);
        const float4* wh4 = reinterpret_cast<const float4*>(
            W_hh + ((size_t)p * 256 + tid) * 64);
        #pragma unroll
        for (int m = 0; m < 16; ++m) {
            float4 v = wi4[m];
            wreg[m * 2 + 0] = ((uint32_t)f2bf(v.y) << 16) | f2bf(v.x);
            wreg[m * 2 + 1] = ((uint32_t)f2bf(v.w) << 16) | f2bf(v.z);
        }
        #pragma unroll
        for (int m = 0; m < 16; ++m) {
            float4 v = wh4[m];
            wreg[32 + m * 2 + 0] = ((uint32_t)f2bf(v.y) << 16) | f2bf(v.x);
            wreg[32 + m * 2 + 1] = ((uint32_t)f2bf(v.w) << 16) | f2bf(v.z);
        }
    }
    const float bias = b_ih[p * 256 + tid] + b_hh[p * 256 + tid];
    const int n = (tid >> 6) & 1, kk = tid & 63;   // roles for tid<128
    float creg = 0.f;
    if (tid < 128) zh[n][64 + kk] = 0.f;
    __syncthreads();

    for (int t = 0; t < 64; ++t) {
        if (tid < 128)
            zh[n][kk] = bf2f(zin[((size_t)(b0 + n) * 64 + t) * 640 + p * 64 + kk]);
        __syncthreads();

        // gates: thread g computes gate row g for both games
        float a0 = bias, a1 = bias;
        #pragma unroll
        for (int jg = 0; jg < 32; ++jg) {
            uint32_t wlo = wreg[jg * 2], whi = wreg[jg * 2 + 1];
            float w0 = __uint_as_float(wlo << 16);
            float w1 = __uint_as_float(wlo & 0xFFFF0000u);
            float w2 = __uint_as_float(whi << 16);
            float w3 = __uint_as_float(whi & 0xFFFF0000u);
            float4 z0 = *reinterpret_cast<const float4*>(&zh[0][jg * 4]);
            float4 z1 = *reinterpret_cast<const float4*>(&zh[1][jg * 4]);
            a0 += w0 * z0.x + w1 * z0.y + w2 * z0.z + w3 * z0.w;
            a1 += w0 * z1.x + w1 * z1.y + w2 * z1.z + w3 * z1.w;
        }
        gbuf[0][tid] = a0; gbuf[1][tid] = a1;
        __syncthreads();

        if (tid < 128) {
            float gi = gbuf[n][kk];
            float gf = gbuf[n][64 + kk];
            float gg = gbuf[n][128 + kk];
            float go = gbuf[n][192 + kk];
            float cn = sigmoidf_(gf) * creg + sigmoidf_(gi) * fast_tanh(gg);
            float hn = sigmoidf_(go) * fast_tanh(cn);
            creg = cn;
            zh[n][64 + kk] = hn;
            out[((size_t)(b0 + n) * 64 + t) * 640 + p * 64 + kk] = hn;
        }
        __syncthreads();
    }
}

extern "C" void kernel_launch(void* const* d_in, const int* in_sizes, int n_in,
                              void* d_out, int out_size, void* d_ws, size_t ws_size,
                              hipStream_t stream) {
    const float* x     = (const float*)d_in[0];
    const float* A_pos = (const float*)d_in[1];
    const float* A_neg = (const float*)d_in[2];
    const float* Wpb   = (const float*)d_in[3];
    const float* bpb   = (const float*)d_in[4];
    const float* Wnb   = (const float*)d_in[5];
    const float* bnb   = (const float*)d_in[6];
    const float* Wpd   = (const float*)d_in[7];
    const float* bpd   = (const float*)d_in[8];
    const float* Wnd   = (const float*)d_in[9];
    const float* bnd   = (const float*)d_in[10];
    const float* Wih   = (const float*)d_in[11];
    const float* Whh   = (const float*)d_in[12];
    const float* bih   = (const float*)d_in[13];
    const float* bhh   = (const float*)d_in[14];

    uint16_t* z = (uint16_t*)d_ws;     // [B,T,P,64] bf16 = 20 MB
    float* out  = (float*)d_out;       // [B,T,P,64] fp32 = 40 MB

    sgcn_kernel<<<(Bg * Tg) / NG, 512, 0, stream>>>(
        x, A_pos, A_neg, Wpb, bpb, Wnb, bnb, Wpd, bpd, Wnd, bnd, z);
    lstm_kernel<<<(Bg / 2) * Pg, 256, 0, stream>>>(
        z, Wih, Whh, bih, bhh, out);
}

// Round 7
// 888.589 us; speedup vs baseline: 1.7401x; 1.7401x over previous
//
#include <hip/hip_runtime.h>
#include <hip/hip_bf16.h>
#include <stdint.h>

// Problem dims
#define Bg 256
#define Tg 64
#define Pg 10
#define NG 8   // graphs per sgcn block

__device__ __forceinline__ uint16_t f2bf(float f) {
    union { float f; uint32_t i; } v; v.f = f;
    uint32_t lsb = (v.i >> 16) & 1u;
    return (uint16_t)((v.i + 0x7FFFu + lsb) >> 16);
}
__device__ __forceinline__ float bf2f(uint16_t u) {
    union { uint32_t i; float f; } v; v.i = ((uint32_t)u) << 16; return v.f;
}
__device__ __forceinline__ float sigmoidf_(float x) {
    return 1.0f / (1.0f + __expf(-x));
}
__device__ __forceinline__ float fast_tanh(float x) {
    // |pre-activation| is bounded (~10) here; no overflow risk at e^{2x}
    float e = __expf(2.0f * x);
    return (e - 1.0f) / (e + 1.0f);
}

// ---------------------------------------------------------------------------
// SGCN v3 (unchanged from round 6: 900 -> ~500us): 8 graphs/block, 512 thr.
// Linearity in base and deep layers; H ping-pong; fp32 weights in LDS.
// ---------------------------------------------------------------------------
__global__ __launch_bounds__(512) void sgcn_kernel(
    const float* __restrict__ x,
    const float* __restrict__ A_pos,
    const float* __restrict__ A_neg,
    const float* __restrict__ Wpb,
    const float* __restrict__ bpb,
    const float* __restrict__ Wnb,
    const float* __restrict__ bnb,
    const float* __restrict__ Wpd,
    const float* __restrict__ bpd,
    const float* __restrict__ Wnd,
    const float* __restrict__ bnd,
    uint16_t* __restrict__ z)
{
    __shared__ __align__(16) float WL[16384];            // 64 KB weight stage
    __shared__ float As[NG][2][10][10];                  // 6.4 KB norm. adj
    __shared__ float rsv[NG][2][10];
    __shared__ __align__(16) float Xs[NG][10][128];      // 40 KB
    __shared__ __align__(16) float Ha[NG][2][10][32];    // 20 KB (ping)
    __shared__ __align__(16) float Hb[NG][2][10][32];    // 20 KB (pong)

    const int tid = threadIdx.x;
    const int bt0 = blockIdx.x * NG;
    const int g = tid >> 6;          // wave-uniform graph
    const int s = (tid >> 5) & 1;    // sign
    const int k = tid & 31;          // output column

    // ---- stage base weights [s][d(0..255)][k], coalesced float4 ----
    {
        const float4* wp = reinterpret_cast<const float4*>(Wpb);
        const float4* wn = reinterpret_cast<const float4*>(Wnb);
        float4* wl = reinterpret_cast<float4*>(WL);
        for (int e = tid; e < 4096; e += 512)
            wl[e] = (e < 2048) ? wp[e] : wn[e - 2048];
    }
    // ---- load X ----
    {
        float4* xs = reinterpret_cast<float4*>(&Xs[0][0][0]);
        for (int e = tid; e < NG * 320; e += 512) {
            int gg = e / 320, r = e - gg * 320;
            xs[e] = reinterpret_cast<const float4*>(
                x + (size_t)(bt0 + gg) * 1280)[r];
        }
    }
    // ---- load raw adjacencies ----
    for (int e = tid; e < NG * 200; e += 512) {
        int gg = e / 200, r = e - gg * 200;
        int sg = r / 100, rr = r - sg * 100;
        (&As[gg][sg][0][0])[rr] =
            (sg ? A_neg : A_pos)[(size_t)(bt0 + gg) * 100 + rr];
    }
    __syncthreads();
    if (tid < NG * 20) {
        int gg = tid / 20, r = tid % 20, sg = r / 10, i = r % 10;
        float sum = 0.f;
        #pragma unroll
        for (int j = 0; j < 10; ++j) sum += As[gg][sg][i][j];
        rsv[gg][sg][i] = 1.0f / (sum + 1e-8f);
    }
    __syncthreads();
    for (int e = tid; e < NG * 200; e += 512) {
        int gg = e / 200, r = e - gg * 200;
        int sg = r / 100, rr = r - sg * 100;
        As[gg][sg][rr / 10][rr % 10] *= rsv[gg][sg][rr / 10];
    }
    __syncthreads();

    // ---- base layer: Y=X@Wtop, Z=X@Wbot (regs); H=tanh(An@Y + Z + b) ----
    {
        float accY[10], accZ[10];
        #pragma unroll
        for (int i = 0; i < 10; ++i) { accY[i] = 0.f; accZ[i] = 0.f; }
        const float* Wt = &WL[s * 8192 + k];
        for (int d = 0; d < 128; d += 4) {
            float wt0 = Wt[(d + 0) * 32], wt1 = Wt[(d + 1) * 32];
            float wt2 = Wt[(d + 2) * 32], wt3 = Wt[(d + 3) * 32];
            float wb0 = Wt[(d + 128) * 32], wb1 = Wt[(d + 129) * 32];
            float wb2 = Wt[(d + 130) * 32], wb3 = Wt[(d + 131) * 32];
            #pragma unroll
            for (int i = 0; i < 10; ++i) {
                float4 xv = *reinterpret_cast<const float4*>(&Xs[g][i][d]);
                accY[i] += xv.x * wt0 + xv.y * wt1 + xv.z * wt2 + xv.w * wt3;
                accZ[i] += xv.x * wb0 + xv.y * wb1 + xv.z * wb2 + xv.w * wb3;
            }
        }
        float bb = (s ? bnb : bpb)[k];
        #pragma unroll
        for (int i = 0; i < 10; ++i) {
            float acc = accZ[i] + bb;
            #pragma unroll
            for (int j = 0; j < 10; ++j)
                acc += As[g][s][i][j] * accY[j];
            Ha[g][s][i][k] = fast_tanh(acc);
        }
    }
    __syncthreads();

    // ---- two deep layers (ping-pong Ha/Hb, no copy) ----
    for (int l = 0; l < 2; ++l) {
        // restage deep weights [s][rk(0..223)][k]
        {
            const float4* wp = reinterpret_cast<const float4*>(Wpd + l * 7168);
            const float4* wn = reinterpret_cast<const float4*>(Wnd + l * 7168);
            float4* wl = reinterpret_cast<float4*>(WL);
            for (int e = tid; e < 3584; e += 512)
                wl[e] = (e < 1792) ? wp[e] : wn[e - 1792];
        }
        __syncthreads();

        const float* Hin = l ? &Hb[0][0][0][0] : &Ha[0][0][0][0];
        float*      Hout = l ? &Ha[0][0][0][0] : &Hb[0][0][0][0];

        float U12[10], U34[10], D[10];
        #pragma unroll
        for (int i = 0; i < 10; ++i) { U12[i] = 0.f; U34[i] = 0.f; D[i] = 0.f; }
        const float* Wd = &WL[s * 7168 + k];
        const float* hpb = Hin + g * 640;        // [g][0][j][c]
        const float* hnb = Hin + g * 640 + 320;  // [g][1][j][c]
        for (int c = 0; c < 32; c += 2) {
            float w10 = Wd[(0 * 32 + c) * 32], w11 = Wd[(0 * 32 + c + 1) * 32];
            float w20 = Wd[(1 * 32 + c) * 32], w21 = Wd[(1 * 32 + c + 1) * 32];
            float w30 = Wd[(2 * 32 + c) * 32], w31 = Wd[(2 * 32 + c + 1) * 32];
            float w40 = Wd[(3 * 32 + c) * 32], w41 = Wd[(3 * 32 + c + 1) * 32];
            float w50 = Wd[(4 * 32 + c) * 32], w51 = Wd[(4 * 32 + c + 1) * 32];
            float w60 = Wd[(5 * 32 + c) * 32], w61 = Wd[(5 * 32 + c + 1) * 32];
            float w70 = Wd[(6 * 32 + c) * 32], w71 = Wd[(6 * 32 + c + 1) * 32];
            #pragma unroll
            for (int j = 0; j < 10; ++j) {
                float2 hp = *reinterpret_cast<const float2*>(hpb + j * 32 + c);
                float2 hn = *reinterpret_cast<const float2*>(hnb + j * 32 + c);
                float2 hs = s ? hn : hp;
                U12[j] += hp.x * w10 + hp.y * w11 + hn.x * w20 + hn.y * w21;
                U34[j] += hp.x * w30 + hp.y * w31 + hn.x * w40 + hn.y * w41;
                D[j]   += hp.x * w50 + hp.y * w51 + hn.x * w60 + hn.y * w61
                        + hs.x * w70 + hs.y * w71;
            }
        }
        float bb = (s ? bnd : bpd)[l * 32 + k];
        #pragma unroll
        for (int i = 0; i < 10; ++i) {
            float acc = D[i] + bb;
            #pragma unroll
            for (int j = 0; j < 10; ++j)
                acc += As[g][0][i][j] * U12[j] + As[g][1][i][j] * U34[j];
            Hout[g * 640 + s * 320 + i * 32 + k] = fast_tanh(acc);
        }
        __syncthreads();
    }

    // ---- z = cat([h_pos, h_neg], -1) as bf16 (final H is in Ha) ----
    {
        uint16_t* zb = z + (size_t)bt0 * 640;
        for (int e = tid; e < NG * 640; e += 512) {
            int gg = e / 640, r = e - gg * 640;
            int i = r >> 6, cc = r & 63, ss = cc >> 5, kk2 = cc & 31;
            zb[e] = f2bf(Ha[gg][ss][i][kk2]);
        }
    }
}

// ---------------------------------------------------------------------------
// LSTM v3: 2 games/block (1280 blocks), NO min-wave launch bound.
// R6 lesson: __launch_bounds__(256,4) capped VGPRs at 64 -> wreg[64] spilled
// to scratch -> 977 MB FETCH, 1016us. Plain (256) lets wreg live in VGPRs.
// ---------------------------------------------------------------------------
__global__ __launch_bounds__(256) void lstm_kernel(
    const uint16_t* __restrict__ zin,
    const float* __restrict__ W_ih,
    const float* __restrict__ W_hh,
    const float* __restrict__ b_ih,
    const float* __restrict__ b_hh,
    float* __restrict__ out)
{
    __shared__ __align__(16) float zh[2][128];   // per game: [z(64) | h(64)]
    __shared__ float gbuf[2][256];               // gate pre-activations

    const int tid = threadIdx.x;
    const int p   = blockIdx.x % 10;
    const int b0  = (blockIdx.x / 10) * 2;

    uint32_t wreg[64];
    {
        const float4* wi4 = reinterpret_cast<const float4*>(
            W_ih + ((size_t)p * 256 + tid) * 64);
        const float4* wh4 = reinterpret_cast<const float4*>(
            W_hh + ((size_t)p * 256 + tid) * 64);
        #pragma unroll
        for (int m = 0; m < 16; ++m) {
            float4 v = wi4[m];
            wreg[m * 2 + 0] = ((uint32_t)f2bf(v.y) << 16) | f2bf(v.x);
            wreg[m * 2 + 1] = ((uint32_t)f2bf(v.w) << 16) | f2bf(v.z);
        }
        #pragma unroll
        for (int m = 0; m < 16; ++m) {
            float4 v = wh4[m];
            wreg[32 + m * 2 + 0] = ((uint32_t)f2bf(v.y) << 16) | f2bf(v.x);
            wreg[32 + m * 2 + 1] = ((uint32_t)f2bf(v.w) << 16) | f2bf(v.z);
        }
    }
    const float bias = b_ih[p * 256 + tid] + b_hh[p * 256 + tid];
    const int n = (tid >> 6) & 1, kk = tid & 63;   // roles for tid<128
    float creg = 0.f;
    if (tid < 128) zh[n][64 + kk] = 0.f;
    __syncthreads();

    for (int t = 0; t < 64; ++t) {
        if (tid < 128)
            zh[n][kk] = bf2f(zin[((size_t)(b0 + n) * 64 + t) * 640 + p * 64 + kk]);
        __syncthreads();

        // gates: thread g computes gate row g for both games
        float a0 = bias, a1 = bias;
        #pragma unroll
        for (int jg = 0; jg < 32; ++jg) {
            uint32_t wlo = wreg[jg * 2], whi = wreg[jg * 2 + 1];
            float w0 = __uint_as_float(wlo << 16);
            float w1 = __uint_as_float(wlo & 0xFFFF0000u);
            float w2 = __uint_as_float(whi << 16);
            float w3 = __uint_as_float(whi & 0xFFFF0000u);
            float4 z0 = *reinterpret_cast<const float4*>(&zh[0][jg * 4]);
            float4 z1 = *reinterpret_cast<const float4*>(&zh[1][jg * 4]);
            a0 += w0 * z0.x + w1 * z0.y + w2 * z0.z + w3 * z0.w;
            a1 += w0 * z1.x + w1 * z1.y + w2 * z1.z + w3 * z1.w;
        }
        gbuf[0][tid] = a0; gbuf[1][tid] = a1;
        __syncthreads();

        if (tid < 128) {
            float gi = gbuf[n][kk];
            float gf = gbuf[n][64 + kk];
            float gg = gbuf[n][128 + kk];
            float go = gbuf[n][192 + kk];
            float cn = sigmoidf_(gf) * creg + sigmoidf_(gi) * fast_tanh(gg);
            float hn = sigmoidf_(go) * fast_tanh(cn);
            creg = cn;
            zh[n][64 + kk] = hn;
            out[((size_t)(b0 + n) * 64 + t) * 640 + p * 64 + kk] = hn;
        }
        __syncthreads();
    }
}

extern "C" void kernel_launch(void* const* d_in, const int* in_sizes, int n_in,
                              void* d_out, int out_size, void* d_ws, size_t ws_size,
                              hipStream_t stream) {
    const float* x     = (const float*)d_in[0];
    const float* A_pos = (const float*)d_in[1];
    const float* A_neg = (const float*)d_in[2];
    const float* Wpb   = (const float*)d_in[3];
    const float* bpb   = (const float*)d_in[4];
    const float* Wnb   = (const float*)d_in[5];
    const float* bnb   = (const float*)d_in[6];
    const float* Wpd   = (const float*)d_in[7];
    const float* bpd   = (const float*)d_in[8];
    const float* Wnd   = (const float*)d_in[9];
    const float* bnd   = (const float*)d_in[10];
    const float* Wih   = (const float*)d_in[11];
    const float* Whh   = (const float*)d_in[12];
    const float* bih   = (const float*)d_in[13];
    const float* bhh   = (const float*)d_in[14];

    uint16_t* z = (uint16_t*)d_ws;     // [B,T,P,64] bf16 = 20 MB
    float* out  = (float*)d_out;       // [B,T,P,64] fp32 = 40 MB

    sgcn_kernel<<<(Bg * Tg) / NG, 512, 0, stream>>>(
        x, A_pos, A_neg, Wpb, bpb, Wnb, bnb, Wpd, bpd, Wnd, bnd, z);
    lstm_kernel<<<(Bg / 2) * Pg, 256, 0, stream>>>(
        z, Wih, Whh, bih, bhh, out);
}